// Round 1
// baseline (20734.386 us; speedup 1.0000x reference)
//
#include <hip/hip_runtime.h>

typedef unsigned long long ull;

#define EMB 512
#define HID 1024
#define NV  32000
#define NB  4
#define NK  8
#define NT  64

__device__ __forceinline__ ull umax64(ull a, ull b) { return a > b ? a : b; }
__device__ __forceinline__ ull umin64(ull a, ull b) { return a < b ? a : b; }

// Total-order key: larger value first, ties -> lower index first (matches jax.lax.top_k)
__device__ __forceinline__ ull packkey(float v, unsigned idx) {
  unsigned u = __float_as_uint(v);
  u ^= (u >> 31) ? 0xFFFFFFFFu : 0x80000000u;
  return ((ull)u << 32) | (ull)(0xFFFFFFFFu - idx);
}

// ---------------------------------------------------------------------------
// prep: hT[k][n] = encoded[n/8][k] (replicate each batch row over 8 beams),
//       last[n] = bos
// ---------------------------------------------------------------------------
__global__ void k_prep(const float* __restrict__ encoded, const int* __restrict__ bosp,
                       int* __restrict__ last, float* __restrict__ hT)
{
  int g = blockIdx.x * 256 + threadIdx.x;   // 32768 = 1024*32
  int k = g >> 5, n = g & 31;
  hT[g] = encoded[(n >> 3) * HID + k];
  if (g < 32) last[g] = *bosp;
}

// ---------------------------------------------------------------------------
// gates GEMM: gatesT[j][n] = sum_k x[n,k]*W[j,k] + b[j]
//   j in [0,3072): W_ih (K=512, x = embedding[last[n]])
//   j in [3072,6144): W_hh (K=1024, x = hT)
// WG = 64 j-columns x 4 K-split groups (one wave each). LDS used to transpose
// coalesced W loads into per-lane columns; no barriers in the K loop (each
// wave only touches its own wlds[kh] slice).
// ---------------------------------------------------------------------------
__global__ __launch_bounds__(256, 2) void k_gates(
    const float* __restrict__ Wih, const float* __restrict__ Whh,
    const float* __restrict__ bih, const float* __restrict__ bhh,
    const float* __restrict__ emb, const int* __restrict__ last,
    const float* __restrict__ hT, float* __restrict__ gatesT)
{
  const int tid = threadIdx.x;
  const int jl = tid & 63;
  const int kh = tid >> 6;
  const int j0 = blockIdx.x * 64;
  const bool is_ih = (j0 < 3 * HID);
  const float* W = is_ih ? Wih : Whh;
  const float* bias = is_ih ? bih : bhh;
  const int jw0 = is_ih ? j0 : (j0 - 3 * HID);
  const int Kd = is_ih ? EMB : HID;
  const int Kq = Kd >> 2;
  const int k0 = kh * Kq;
  const int nchunk = Kq >> 5;

  __shared__ float wlds[4][32][65];

  float acc[32];
#pragma unroll
  for (int n = 0; n < 32; ++n) acc[n] = 0.f;

  const float* eb[32];
  if (is_ih) {
#pragma unroll
    for (int n = 0; n < 32; ++n) eb[n] = emb + (size_t)last[n] * EMB;
  }

  for (int it = 0; it < nchunk; ++it) {
    const int kb = k0 + it * 32;
#pragma unroll
    for (int m = 0; m < 32; ++m) {
      int flat = m * 64 + jl;
      int jr = flat >> 5;
      int kc = flat & 31;
      wlds[kh][kc][jr] = W[(size_t)(jw0 + jr) * Kd + kb + kc];
    }
    float wreg[32];
#pragma unroll
    for (int k = 0; k < 32; ++k) wreg[k] = wlds[kh][k][jl];

    if (is_ih) {
      // x rows are per-n embedding rows (stride-1 in k): n-outer, split accumulators
#pragma unroll
      for (int n = 0; n < 32; ++n) {
        const float* xr = eb[n] + kb;
        float a0 = 0.f, a1 = 0.f, a2 = 0.f, a3 = 0.f;
#pragma unroll
        for (int k8 = 0; k8 < 8; ++k8) {
          a0 = fmaf(wreg[4 * k8 + 0], xr[4 * k8 + 0], a0);
          a1 = fmaf(wreg[4 * k8 + 1], xr[4 * k8 + 1], a1);
          a2 = fmaf(wreg[4 * k8 + 2], xr[4 * k8 + 2], a2);
          a3 = fmaf(wreg[4 * k8 + 3], xr[4 * k8 + 3], a3);
        }
        acc[n] += (a0 + a1) + (a2 + a3);
      }
    } else {
      // x = hT[k][n]: contiguous 32 floats per k -> merged scalar loads
#pragma unroll
      for (int k = 0; k < 32; ++k) {
        const float* xr = hT + (size_t)(kb + k) * 32;
#pragma unroll
        for (int n = 0; n < 32; ++n) acc[n] = fmaf(wreg[k], xr[n], acc[n]);
      }
    }
  }

  __syncthreads();
  float* ex = (float*)wlds;   // reuse as [3][32][64]
  if (kh > 0) {
#pragma unroll
    for (int n = 0; n < 32; ++n) ex[((kh - 1) * 32 + n) * 64 + jl] = acc[n];
  }
  __syncthreads();
  if (kh == 0) {
#pragma unroll
    for (int n = 0; n < 32; ++n)
      acc[n] += ex[n * 64 + jl] + ex[(32 + n) * 64 + jl] + ex[(64 + n) * 64 + jl];
    float bv = bias[jw0 + jl];
#pragma unroll
    for (int n = 0; n < 32; ++n) acc[n] += bv;
    float4* o = (float4*)(gatesT + (size_t)(j0 + jl) * 32);
#pragma unroll
    for (int q = 0; q < 8; ++q)
      o[q] = make_float4(acc[4 * q], acc[4 * q + 1], acc[4 * q + 2], acc[4 * q + 3]);
  }
}

// ---------------------------------------------------------------------------
// GRU elementwise combine: h2 = (1-z)*tanh(gi_n + r*gh_n) + z*h
// ---------------------------------------------------------------------------
__global__ __launch_bounds__(256) void k_combine(const float* __restrict__ gatesT,
                                                 const float* __restrict__ hT,
                                                 float* __restrict__ h2T)
{
  int g = blockIdx.x * 256 + threadIdx.x;   // 32768
  int i = g >> 5, n = g & 31;
  float gi_r = gatesT[(0 * HID + i) * 32 + n];
  float gi_z = gatesT[(1 * HID + i) * 32 + n];
  float gi_n = gatesT[(2 * HID + i) * 32 + n];
  float gh_r = gatesT[(3 * HID + i) * 32 + n];
  float gh_z = gatesT[(4 * HID + i) * 32 + n];
  float gh_n = gatesT[(5 * HID + i) * 32 + n];
  float r = 1.f / (1.f + expf(-(gi_r + gh_r)));
  float z = 1.f / (1.f + expf(-(gi_z + gh_z)));
  float nn = tanhf(gi_n + r * gh_n);
  h2T[g] = (1.f - z) * nn + z * hT[g];
}

// ---------------------------------------------------------------------------
// logits GEMM + per-WG logsumexp partials.
// logitsT[v][n] = h2[n,:] . Wout[v,:] + bout[v]
// ---------------------------------------------------------------------------
__global__ __launch_bounds__(256, 2) void k_logits(
    const float* __restrict__ Wout, const float* __restrict__ bout,
    const float* __restrict__ h2T, float* __restrict__ logitsT,
    float* __restrict__ lsePart)
{
  const int tid = threadIdx.x;
  const int jl = tid & 63;
  const int kh = tid >> 6;
  const int j0 = blockIdx.x * 64;

  __shared__ float wlds[4][32][65];

  float acc[32];
#pragma unroll
  for (int n = 0; n < 32; ++n) acc[n] = 0.f;

  const int Kq = HID >> 2;   // 256
  const int k0 = kh * Kq;

  for (int it = 0; it < Kq / 32; ++it) {
    const int kb = k0 + it * 32;
#pragma unroll
    for (int m = 0; m < 32; ++m) {
      int flat = m * 64 + jl;
      int jr = flat >> 5;
      int kc = flat & 31;
      wlds[kh][kc][jr] = Wout[(size_t)(j0 + jr) * HID + kb + kc];
    }
    float wreg[32];
#pragma unroll
    for (int k = 0; k < 32; ++k) wreg[k] = wlds[kh][k][jl];
#pragma unroll
    for (int k = 0; k < 32; ++k) {
      const float* xr = h2T + (size_t)(kb + k) * 32;
#pragma unroll
      for (int n = 0; n < 32; ++n) acc[n] = fmaf(wreg[k], xr[n], acc[n]);
    }
  }

  __syncthreads();
  float* ex = (float*)wlds;
  if (kh > 0) {
#pragma unroll
    for (int n = 0; n < 32; ++n) ex[((kh - 1) * 32 + n) * 64 + jl] = acc[n];
  }
  __syncthreads();
  if (kh == 0) {
#pragma unroll
    for (int n = 0; n < 32; ++n)
      acc[n] += ex[n * 64 + jl] + ex[(32 + n) * 64 + jl] + ex[(64 + n) * 64 + jl];
    float bv = bout[j0 + jl];
#pragma unroll
    for (int n = 0; n < 32; ++n) acc[n] += bv;
    float4* o = (float4*)(logitsT + (size_t)(j0 + jl) * 32);
#pragma unroll
    for (int q = 0; q < 8; ++q)
      o[q] = make_float4(acc[4 * q], acc[4 * q + 1], acc[4 * q + 2], acc[4 * q + 3]);
    // online-lse partial over this WG's 64 columns, per row n
#pragma unroll 1
    for (int n = 0; n < 32; ++n) {
      float M = acc[n];
#pragma unroll
      for (int off = 1; off < 64; off <<= 1) M = fmaxf(M, __shfl_xor(M, off, 64));
      float s = expf(acc[n] - M);
#pragma unroll
      for (int off = 1; off < 64; off <<= 1) s += __shfl_xor(s, off, 64);
      if (tid == 0) {
        lsePart[((size_t)blockIdx.x * 32 + n) * 2] = M;
        lsePart[((size_t)blockIdx.x * 32 + n) * 2 + 1] = s;
      }
    }
  }
}

// ---------------------------------------------------------------------------
// topkA: 32 WGs per batch. Phase 1: finish logsumexp A[n] = M + log(sum).
// Phase 2: per-thread sorted top-8 over the chunk's candidates, then exact
// 8-round max extraction across the WG (keys are unique).
// mode 0: step-0 (candidates = lp over V, row b*8). mode 1: beam step.
// ---------------------------------------------------------------------------
__global__ __launch_bounds__(256) void k_topkA(
    const float* __restrict__ logitsT, const float* __restrict__ lsePart,
    const float* __restrict__ prev_vals, const int* __restrict__ prev_tok,
    const int* __restrict__ eosp, ull* __restrict__ top8A, int mode)
{
  const int tid = threadIdx.x;
  const int b = blockIdx.x >> 5;
  const int c = blockIdx.x & 31;

  __shared__ float pm[32][8];
  __shared__ float ps[32][8];
  __shared__ float A[8];
  __shared__ ull wm[4];

  {
    const int n8 = tid & 7;
    const int grp = tid >> 3;
    float m = -3.0e38f, s = 0.f;
    for (int p = grp; p < 500; p += 32) {
      const float* q = lsePart + ((size_t)p * 32 + b * 8 + n8) * 2;
      float m2 = q[0], s2 = q[1];
      float Mx = fmaxf(m, m2);
      s = s * expf(m - Mx) + s2 * expf(m2 - Mx);
      m = Mx;
    }
    pm[grp][n8] = m; ps[grp][n8] = s;
    __syncthreads();
    for (int off2 = 16; off2 >= 1; off2 >>= 1) {
      if (grp < off2) {
        float m1 = pm[grp][n8], s1 = ps[grp][n8];
        float m2 = pm[grp + off2][n8], s2 = ps[grp + off2][n8];
        float Mx = fmaxf(m1, m2);
        pm[grp][n8] = Mx;
        ps[grp][n8] = s1 * expf(m1 - Mx) + s2 * expf(m2 - Mx);
      }
      __syncthreads();
    }
    if (tid < 8) A[tid] = pm[0][tid] + logf(ps[0][tid]);
    __syncthreads();
  }

  const int eos = *eosp;
  float Al[8], pv[8]; int pt[8];
#pragma unroll
  for (int j = 0; j < 8; ++j) { Al[j] = A[j]; pv[j] = prev_vals[b * 8 + j]; pt[j] = prev_tok[b * 8 + j]; }

  ull t8[8];
#pragma unroll
  for (int j = 0; j < 8; ++j) t8[j] = 0ULL;

  if (mode == 1) {
    const int base = c * 8000;
    for (int i = base + tid; i < base + 8000; i += 256) {
      int kb = i / NV;
      int v = i - kb * NV;
      float val;
      if (pt[kb] == eos) val = (v == eos) ? 0.f : -1e30f;
      else val = pv[kb] + (logitsT[(size_t)v * 32 + b * 8 + kb] - Al[kb]);
      ull key = packkey(val, (unsigned)i);
      if (key > t8[7]) {
        t8[7] = key;
#pragma unroll
        for (int q = 7; q >= 1; --q) {
          ull hi = umax64(t8[q - 1], t8[q]);
          ull lo = umin64(t8[q - 1], t8[q]);
          t8[q - 1] = hi; t8[q] = lo;
        }
      }
    }
  } else {
    const int base = c * 1000;
    for (int i = base + tid; i < base + 1000; i += 256) {
      float val = logitsT[(size_t)i * 32 + b * 8] - Al[0];
      ull key = packkey(val, (unsigned)i);
      if (key > t8[7]) {
        t8[7] = key;
#pragma unroll
        for (int q = 7; q >= 1; --q) {
          ull hi = umax64(t8[q - 1], t8[q]);
          ull lo = umin64(t8[q - 1], t8[q]);
          t8[q - 1] = hi; t8[q] = lo;
        }
      }
    }
  }

  int pi = 0;
  for (int r = 0; r < 8; ++r) {
    ull cand = (pi < 8) ? t8[pi] : 0ULL;
#pragma unroll
    for (int off = 1; off < 64; off <<= 1) cand = umax64(cand, __shfl_xor(cand, off, 64));
    if ((tid & 63) == 0) wm[tid >> 6] = cand;
    __syncthreads();
    ull win = umax64(umax64(wm[0], wm[1]), umax64(wm[2], wm[3]));
    if (pi < 8 && t8[pi] == win) ++pi;
    if (tid == 0) top8A[((size_t)b * 32 + c) * 8 + r] = win;
    __syncthreads();
  }
}

// ---------------------------------------------------------------------------
// topkB: per batch, merge 32x8 chunk winners -> final top-8 in order, commit
// beam state, gather histories (ping-pong) and hidden columns.
// ---------------------------------------------------------------------------
__global__ __launch_bounds__(256) void k_topkB(
    const ull* __restrict__ top8A,
    float* __restrict__ prev_vals, int* __restrict__ prev_tok, int* __restrict__ last,
    const float* __restrict__ lp_src, float* __restrict__ lp_dst,
    const int* __restrict__ tok_src, int* __restrict__ tok_dst,
    const float* __restrict__ h2T, float* __restrict__ hT,
    int step, int mode)
{
  const int tid = threadIdx.x;
  const int b = blockIdx.x;
  __shared__ ull wm[4];
  __shared__ float vals8[8];
  __shared__ int tok8[8];
  __shared__ int which8[8];

  ull mykey = top8A[(size_t)b * 256 + tid];
  int done = 0;
  for (int r = 0; r < 8; ++r) {
    ull cand = done ? 0ULL : mykey;
#pragma unroll
    for (int off = 1; off < 64; off <<= 1) cand = umax64(cand, __shfl_xor(cand, off, 64));
    if ((tid & 63) == 0) wm[tid >> 6] = cand;
    __syncthreads();
    ull win = umax64(umax64(wm[0], wm[1]), umax64(wm[2], wm[3]));
    if (!done && mykey == win) done = 1;
    if (tid == 0) {
      unsigned idx = 0xFFFFFFFFu - (unsigned)(win & 0xFFFFFFFFull);
      unsigned u = (unsigned)(win >> 32);
      u = (u >> 31) ? (u ^ 0x80000000u) : ~u;
      vals8[r] = __uint_as_float(u);
      if (mode == 1) { tok8[r] = (int)(idx % NV); which8[r] = (int)(idx / NV); }
      else { tok8[r] = (int)idx; which8[r] = r; }
    }
    __syncthreads();
  }

  if (tid < 8) {
    prev_vals[b * 8 + tid] = vals8[tid];
    prev_tok[b * 8 + tid] = tok8[tid];
    last[b * 8 + tid] = tok8[tid];
  }
  for (int idx = tid; idx < 512; idx += 256) {
    int j = idx >> 6;
    int tt = idx & 63;
    float lv; int tv;
    if (tt == step) { lv = vals8[j]; tv = tok8[j]; }
    else if (mode == 0) { lv = 0.f; tv = 0; }
    else {
      int w = which8[j];
      lv = lp_src[b * 512 + w * 64 + tt];
      tv = tok_src[b * 512 + w * 64 + tt];
    }
    lp_dst[b * 512 + idx] = lv;
    tok_dst[b * 512 + idx] = tv;
  }
  for (int idx = tid; idx < 8192; idx += 256) {
    int kk = idx >> 3;
    int j = idx & 7;
    hT[kk * 32 + b * 8 + j] = h2T[kk * 32 + b * 8 + which8[j]];
  }
}

// ---------------------------------------------------------------------------
// final: d_out = [lp_hist (2048 floats), tok_hist as floats (2048)]
// ---------------------------------------------------------------------------
__global__ void k_final(const float* __restrict__ lp_hist, const int* __restrict__ tok_hist,
                        float* __restrict__ out)
{
  int g = blockIdx.x * 256 + threadIdx.x;   // 4096
  if (g < 2048) out[g] = lp_hist[g];
  else out[g] = (float)tok_hist[g - 2048];
}

extern "C" void kernel_launch(void* const* d_in, const int* in_sizes, int n_in,
                              void* d_out, int out_size, void* d_ws, size_t ws_size,
                              hipStream_t stream)
{
  (void)in_sizes; (void)n_in; (void)out_size; (void)ws_size;
  const float* encoded   = (const float*)d_in[0];
  const float* embedding = (const float*)d_in[1];
  const float* Wih       = (const float*)d_in[2];
  const float* Whh       = (const float*)d_in[3];
  const float* bih       = (const float*)d_in[4];
  const float* bhh       = (const float*)d_in[5];
  const float* Wout      = (const float*)d_in[6];
  const float* bout      = (const float*)d_in[7];
  const int*   bosp      = (const int*)d_in[8];
  const int*   eosp      = (const int*)d_in[9];

  char* p = (char*)d_ws;
  size_t off = 0;
  auto ALLOC = [&](size_t bytes) -> void* {
    void* r = p + off;
    off += (bytes + 255) & ~(size_t)255;
    return r;
  };
  float* hT        = (float*)ALLOC((size_t)HID * 32 * 4);
  float* h2T       = (float*)ALLOC((size_t)HID * 32 * 4);
  float* gatesT    = (float*)ALLOC((size_t)6 * HID * 32 * 4);
  float* logitsT   = (float*)ALLOC((size_t)NV * 32 * 4);
  float* lsePart   = (float*)ALLOC((size_t)500 * 32 * 2 * 4);
  ull*   top8A     = (ull*)ALLOC((size_t)NB * 32 * 8 * 8);
  float* prev_vals = (float*)ALLOC(32 * 4);
  int*   prev_tok  = (int*)ALLOC(32 * 4);
  int*   last      = (int*)ALLOC(32 * 4);
  float* lp0       = (float*)ALLOC(2048 * 4);
  float* lp1       = (float*)ALLOC(2048 * 4);
  int*   tok0      = (int*)ALLOC(2048 * 4);
  int*   tok1      = (int*)ALLOC(2048 * 4);

  k_prep<<<128, 256, 0, stream>>>(encoded, bosp, last, hT);
  for (int t = 0; t < NT; ++t) {
    k_gates<<<96, 256, 0, stream>>>(Wih, Whh, bih, bhh, embedding, last, hT, gatesT);
    k_combine<<<128, 256, 0, stream>>>(gatesT, hT, h2T);
    k_logits<<<500, 256, 0, stream>>>(Wout, bout, h2T, logitsT, lsePart);
    const int mode = (t == 0) ? 0 : 1;
    k_topkA<<<128, 256, 0, stream>>>(logitsT, lsePart, prev_vals, prev_tok, eosp, top8A, mode);
    float* lps = (t & 1) ? lp0 : lp1;
    float* lpd = (t & 1) ? lp1 : lp0;
    int*   tks = (t & 1) ? tok0 : tok1;
    int*   tkd = (t & 1) ? tok1 : tok0;
    k_topkB<<<NB, 256, 0, stream>>>(top8A, prev_vals, prev_tok, last, lps, lpd, tks, tkd, h2T, hT, t, mode);
  }
  k_final<<<16, 256, 0, stream>>>(lp1, tok1, (float*)d_out);
}